// Round 1
// baseline (1115.259 us; speedup 1.0000x reference)
//
#include <hip/hip_runtime.h>
#include <hip/hip_bf16.h>

#define I_SZ 834
#define H_SZ 190
#define F_SZ 250
#define O_SZ 512
#define T_SZ 256
#define K_SZ 1024   // I+H
#define N3  47500   // F*H

// -------- K1: P[t][h] = Wrnn[h, H:]·x[t] + brnn[h] --------------------------
__global__ void __launch_bounds__(256) k1_xproj(const float* __restrict__ x,
                                                const float* __restrict__ Wrnn,
                                                const float* __restrict__ brnn,
                                                float* __restrict__ P) {
    __shared__ float xs[I_SZ];
    int t = blockIdx.x;
    for (int i = threadIdx.x; i < I_SZ; i += 256) xs[i] = x[t * I_SZ + i];
    __syncthreads();
    int wave = threadIdx.x >> 6, lane = threadIdx.x & 63;
    for (int h = wave; h < H_SZ; h += 4) {
        const float* wr = Wrnn + h * K_SZ + H_SZ;  // x-part of row h
        float s = 0.f;
        for (int i = lane; i < I_SZ; i += 64) s += wr[i] * xs[i];
        #pragma unroll
        for (int off = 32; off; off >>= 1) s += __shfl_xor(s, off, 64);
        if (lane == 0) P[t * H_SZ + h] = s + brnn[h];
    }
}

// -------- K2: sequential scan, one workgroup, Whh in LDS --------------------
__global__ void __launch_bounds__(256) k2_scan(const float* __restrict__ Wrnn,
                                               const float* __restrict__ h0,
                                               const float* __restrict__ P,
                                               float* __restrict__ h_all,
                                               float* __restrict__ S) {
    __shared__ float Whh[H_SZ * 193];   // padded stride 193 to spread banks
    __shared__ float hprev[H_SZ];
    int tid = threadIdx.x;
    for (int idx = tid; idx < H_SZ * H_SZ; idx += 256) {
        int h = idx / H_SZ, k = idx - h * H_SZ;
        Whh[h * 193 + k] = Wrnn[h * K_SZ + k];
    }
    if (tid < H_SZ) hprev[tid] = h0[tid];
    __syncthreads();
    float Srun = 0.f;
    for (int t = 0; t < T_SZ; ++t) {
        float v = 0.f;
        if (tid < H_SZ) {
            const float* w = &Whh[tid * 193];
            float s0 = 0.f, s1 = 0.f;
            for (int k = 0; k < H_SZ; k += 2) {
                s0 += w[k]     * hprev[k];
                s1 += w[k + 1] * hprev[k + 1];
            }
            v = tanhf(s0 + s1 + P[t * H_SZ + tid]);
            S[t * H_SZ + tid] = Srun;       // prefix sum BEFORE adding h_t
            h_all[t * H_SZ + tid] = v;
        }
        __syncthreads();
        if (tid < H_SZ) { hprev[tid] = v; Srun += v; }
        __syncthreads();
    }
}

// -------- K2b: A[t] = [x_t | h_t] -------------------------------------------
__global__ void __launch_bounds__(256) k2b_buildA(const float* __restrict__ x,
                                                  const float* __restrict__ h_all,
                                                  float* __restrict__ A) {
    int t = blockIdx.x;
    for (int i = threadIdx.x; i < K_SZ; i += 256)
        A[t * K_SZ + i] = (i < I_SZ) ? x[t * I_SZ + i] : h_all[t * H_SZ + (i - I_SZ)];
}

// -------- K3: z'[t][j] = sum_h S[t][h] * (A @ W3)[t, j*190+h] ---------------
// One block per j. C-tile [256 x 190] kept in registers, contracted vs S.
#define BK 32
__global__ void __launch_bounds__(1024) k3_big(const float* __restrict__ A,
                                               const float* __restrict__ Wupd,
                                               const float* __restrict__ S,
                                               float* __restrict__ zprime) {
    __shared__ float As[BK * 260];     // As[k][m], padded row 260 (16B-aligned rows)
    __shared__ float Bs[BK * 192];     // Bs[k][n], cols 190/191 zeroed
    __shared__ float part[256 * 33];   // per-m partials across 32 n-groups
    int j = blockIdx.x;
    int tid = threadIdx.x;
    int tm = tid & 31, tn = tid >> 5;  // tm: m-group 0..31, tn: n-group 0..31
    float acc[8][6];
    #pragma unroll
    for (int r = 0; r < 8; ++r)
        #pragma unroll
        for (int c = 0; c < 6; ++c) acc[r][c] = 0.f;

    const float* Wb = Wupd + j * H_SZ;
    for (int k0 = 0; k0 < K_SZ; k0 += BK) {
        #pragma unroll
        for (int it = 0; it < 2; ++it) {        // A tile: 2048 float4 / 1024 thr
            int slot = tid + it * 1024;
            int m = slot >> 3, kq = slot & 7;
            const float4 v = *reinterpret_cast<const float4*>(A + m * K_SZ + k0 + kq * 4);
            As[(kq * 4 + 0) * 260 + m] = v.x;
            As[(kq * 4 + 1) * 260 + m] = v.y;
            As[(kq * 4 + 2) * 260 + m] = v.z;
            As[(kq * 4 + 3) * 260 + m] = v.w;
        }
        #pragma unroll
        for (int it = 0; it < 6; ++it) {        // B tile: 32x192 = 6144 / 1024 thr
            int idx = tid + it * 1024;
            int row = idx / 192, col = idx - row * 192;
            Bs[idx] = (col < H_SZ) ? Wb[(k0 + row) * N3 + col] : 0.f;
        }
        __syncthreads();
        #pragma unroll
        for (int kk = 0; kk < BK; ++kk) {
            float a[8], b[6];
            #pragma unroll
            for (int r = 0; r < 8; ++r) a[r] = As[kk * 260 + tm * 8 + r];
            #pragma unroll
            for (int c = 0; c < 6; ++c) b[c] = Bs[kk * 192 + tn * 6 + c];
            #pragma unroll
            for (int r = 0; r < 8; ++r)
                #pragma unroll
                for (int c = 0; c < 6; ++c) acc[r][c] += a[r] * b[c];
        }
        __syncthreads();
    }
    // epilogue: contract against S over h, reduce across n-groups
    #pragma unroll
    for (int r = 0; r < 8; ++r) {
        int m = tm * 8 + r;
        float p = 0.f;
        #pragma unroll
        for (int c = 0; c < 6; ++c) {
            int h = tn * 6 + c;
            if (h < H_SZ) p += acc[r][c] * S[m * H_SZ + h];
        }
        part[m * 33 + tn] = p;
    }
    __syncthreads();
    if (tid < 256) {
        int m = tid;
        float z = 0.f;
        #pragma unroll
        for (int q = 0; q < 32; ++q) z += part[m * 33 + q];
        zprime[m * F_SZ + j] = z;
    }
}

// -------- K4: z -> selu -> @W2 + b2 -----------------------------------------
__global__ void __launch_bounds__(256) k4_out(const float* __restrict__ A,
                                              const float* __restrict__ W1,
                                              const float* __restrict__ bupd,
                                              const float* __restrict__ b1,
                                              const float* __restrict__ W2,
                                              const float* __restrict__ b2,
                                              const float* __restrict__ zprime,
                                              float* __restrict__ out) {
    __shared__ float as[K_SZ];
    __shared__ float ys[256];
    int t = blockIdx.x;
    int tid = threadIdx.x;
    for (int i = tid; i < K_SZ; i += 256) as[i] = A[t * K_SZ + i];
    __syncthreads();
    if (tid < F_SZ) {
        float d1 = 0.f, d2 = 0.f;
        #pragma unroll 4
        for (int i = 0; i < K_SZ; ++i) {
            float av = as[i];
            d1 += av * W1[i * F_SZ + tid];
            d2 += av * bupd[i * F_SZ + tid];
        }
        float z = zprime[t * F_SZ + tid] + d1 + (float)t * d2 + b1[tid];
        const float scale = 1.0507009873554805f, alpha = 1.6732632423543772f;
        ys[tid] = z > 0.f ? scale * z : scale * alpha * (expf(z) - 1.f);
    }
    __syncthreads();
    #pragma unroll
    for (int rep = 0; rep < 2; ++rep) {
        int o = tid + rep * 256;
        float s = 0.f;
        #pragma unroll 2
        for (int jj = 0; jj < F_SZ; ++jj) s += ys[jj] * W2[jj * O_SZ + o];
        out[t * O_SZ + o] = s + b2[o];
    }
}

extern "C" void kernel_launch(void* const* d_in, const int* in_sizes, int n_in,
                              void* d_out, int out_size, void* d_ws, size_t ws_size,
                              hipStream_t stream) {
    const float* x    = (const float*)d_in[0];
    const float* h0   = (const float*)d_in[1];
    const float* Wrnn = (const float*)d_in[2];
    const float* brnn = (const float*)d_in[3];
    const float* Wupd = (const float*)d_in[4];
    const float* bupd = (const float*)d_in[5];
    const float* W1   = (const float*)d_in[6];
    const float* b1   = (const float*)d_in[7];
    const float* W2   = (const float*)d_in[8];
    const float* b2   = (const float*)d_in[9];
    float* out = (float*)d_out;

    float* ws = (float*)d_ws;
    float* P      = ws;                          // 256*190
    float* h_all  = P + T_SZ * H_SZ;             // 256*190
    float* S      = h_all + T_SZ * H_SZ;         // 256*190
    float* A      = S + T_SZ * H_SZ;             // 256*1024 (16B-aligned offset)
    float* zprime = A + T_SZ * K_SZ;             // 256*250

    k1_xproj<<<T_SZ, 256, 0, stream>>>(x, Wrnn, brnn, P);
    k2_scan<<<1, 256, 0, stream>>>(Wrnn, h0, P, h_all, S);
    k2b_buildA<<<T_SZ, 256, 0, stream>>>(x, h_all, A);
    k3_big<<<F_SZ, 1024, 0, stream>>>(A, Wupd, S, zprime);
    k4_out<<<T_SZ, 256, 0, stream>>>(A, W1, bupd, b1, W2, b2, zprime, out);
}

// Round 2
// 831.019 us; speedup vs baseline: 1.3420x; 1.3420x over previous
//
#include <hip/hip_runtime.h>
#include <hip/hip_bf16.h>

#define I_SZ 834
#define H_SZ 190
#define F_SZ 250
#define O_SZ 512
#define T_SZ 256
#define K_SZ 1024   // I+H
#define NW   47500  // F*H = W3 row stride (Wupd flat IS W3 row-major)
#define BNP  193    // padded LDS row for B tile

typedef __attribute__((ext_vector_type(8))) short short8;
typedef __attribute__((ext_vector_type(4))) float f32x4;

__device__ __forceinline__ short f2bf(float f) {
    union { __hip_bfloat16 h; short s; } u;
    u.h = __float2bfloat16(f);
    return u.s;
}

// -------- K1: P[t][h] = Wrnn[h, H:]·x[t] + brnn[h] --------------------------
__global__ void __launch_bounds__(256) k1_xproj(const float* __restrict__ x,
                                                const float* __restrict__ Wrnn,
                                                const float* __restrict__ brnn,
                                                float* __restrict__ P) {
    __shared__ float xs[I_SZ];
    int t = blockIdx.x;
    for (int i = threadIdx.x; i < I_SZ; i += 256) xs[i] = x[t * I_SZ + i];
    __syncthreads();
    int wave = threadIdx.x >> 6, lane = threadIdx.x & 63;
    for (int h = wave; h < H_SZ; h += 4) {
        const float* wr = Wrnn + h * K_SZ + H_SZ;  // x-part of row h
        float s = 0.f;
        for (int i = lane; i < I_SZ; i += 64) s += wr[i] * xs[i];
        #pragma unroll
        for (int off = 32; off; off >>= 1) s += __shfl_xor(s, off, 64);
        if (lane == 0) P[t * H_SZ + h] = s + brnn[h];
    }
}

// -------- K2: sequential scan; W row in REGISTERS, hprev LDS dbuf -----------
__global__ void __launch_bounds__(256, 1) k2_scan(const float* __restrict__ Wrnn,
                                                  const float* __restrict__ h0,
                                                  const float* __restrict__ P,
                                                  float* __restrict__ h_all,
                                                  float* __restrict__ S) {
    __shared__ __align__(16) float hbuf0[192];
    __shared__ __align__(16) float hbuf1[192];
    const int tid = threadIdx.x;
    const int h = tid;
    float w[192];
    if (h < H_SZ) {
        #pragma unroll
        for (int k = 0; k < 192; ++k)
            w[k] = (k < H_SZ) ? Wrnn[h * K_SZ + k] : 0.f;
    }
    if (tid < 192) {
        hbuf0[tid] = (tid < H_SZ) ? h0[tid] : 0.f;
        hbuf1[tid] = 0.f;
    }
    __syncthreads();
    float Srun = 0.f;
    for (int t = 0; t < T_SZ; ++t) {
        const float* hb = (t & 1) ? hbuf1 : hbuf0;
        float* hn       = (t & 1) ? hbuf0 : hbuf1;
        if (h < H_SZ) {
            float a0 = 0.f, a1 = 0.f, a2 = 0.f, a3 = 0.f;
            const float4* hb4 = reinterpret_cast<const float4*>(hb);
            #pragma unroll
            for (int q = 0; q < 48; ++q) {
                float4 hv = hb4[q];
                a0 += w[q * 4 + 0] * hv.x;
                a1 += w[q * 4 + 1] * hv.y;
                a2 += w[q * 4 + 2] * hv.z;
                a3 += w[q * 4 + 3] * hv.w;
            }
            float v = tanhf(a0 + a1 + a2 + a3 + P[t * H_SZ + h]);
            S[t * H_SZ + h] = Srun;          // prefix EXCLUDING current step
            h_all[t * H_SZ + h] = v;
            hn[h] = v;
            Srun += v;
        }
        __syncthreads();
    }
}

// -------- K2b: Abf[t][k] = bf16(concat(x_t, h_t)) ---------------------------
__global__ void __launch_bounds__(256) k2b_buildA(const float* __restrict__ x,
                                                  const float* __restrict__ h_all,
                                                  short* __restrict__ Abf) {
    int t = blockIdx.x;
    for (int i = threadIdx.x; i < K_SZ; i += 256) {
        float v = (i < I_SZ) ? x[t * I_SZ + i] : h_all[t * H_SZ + (i - I_SZ)];
        Abf[t * K_SZ + i] = f2bf(v);
    }
}

// -------- K3: MFMA GEMM (A[256x1024]bf16 @ W3[1024x190-per-j]) fused with S -
// Block per j. 8 waves = 2 (M) x 4 (N). Wave: 8 m-tiles x 3 n-tiles of 16x16.
__global__ void __launch_bounds__(512, 2) k3_mfma(const float* __restrict__ Wupd,
                                                  const short* __restrict__ Abf,
                                                  const float* __restrict__ S,
                                                  float* __restrict__ zprime) {
    __shared__ float Bs[32 * BNP];      // fp32 staging tile [k=32][n=193]
    __shared__ float part[T_SZ * 4];    // per-row partials from the 4 n-waves
    const int tid = threadIdx.x;
    const int j = blockIdx.x;
    const int l = tid & 63;
    const int wv = tid >> 6;
    const int wm = wv >> 2;             // 0..1 : m-half
    const int wn = wv & 3;              // 0..3 : n-quarter (48 cols)
    const int l15 = l & 15, lg = l >> 4;

    // zero the pad columns 190..192 once (reads touch 190,191)
    if (tid < 96) {
        int r = tid / 3, c = tid - r * 3;
        Bs[r * BNP + 190 + c] = 0.f;
    }

    // staging assignment: 32*190 = 6080 elements over 512 threads (12 each)
    int goff[12], loff[12];
    #pragma unroll
    for (int i = 0; i < 12; ++i) {
        int e = tid + i * 512;
        if (e < 6080) {
            int r = e / 190, c = e - r * 190;
            goff[i] = r * NW + j * H_SZ + c;
            loff[i] = r * BNP + c;
        } else { goff[i] = 0; loff[i] = -1; }
    }
    float f[12];
    #pragma unroll
    for (int i = 0; i < 12; ++i) if (loff[i] >= 0) f[i] = Wupd[goff[i]];

    f32x4 acc[8][3];
    #pragma unroll
    for (int mt = 0; mt < 8; ++mt)
        #pragma unroll
        for (int nt = 0; nt < 3; ++nt) acc[mt][nt] = (f32x4){0.f, 0.f, 0.f, 0.f};

    const int arow = wm * 128 + l15;
    const int kgrp = lg * 8;            // k-offset of this lane group

    for (int ks = 0; ks < 32; ++ks) {
        __syncthreads();                              // Bs free (prev reads done)
        #pragma unroll
        for (int i = 0; i < 12; ++i) if (loff[i] >= 0) Bs[loff[i]] = f[i];
        __syncthreads();
        if (ks < 31) {                                // prefetch next k-slab (HBM)
            const float* Wn = Wupd + (size_t)(ks + 1) * 32 * NW;
            #pragma unroll
            for (int i = 0; i < 12; ++i) if (loff[i] >= 0) f[i] = Wn[goff[i]];
        }
        short8 a[8];
        #pragma unroll
        for (int mt = 0; mt < 8; ++mt) {              // A-frags straight from L2
            const short* ap = Abf + (size_t)(arow + mt * 16) * K_SZ + ks * 32 + kgrp;
            a[mt] = *reinterpret_cast<const short8*>(ap);
        }
        #pragma unroll
        for (int nt = 0; nt < 3; ++nt) {
            const int nloc = wn * 48 + nt * 16 + l15;
            const int bbase = kgrp * BNP + nloc;
            short8 b;
            #pragma unroll
            for (int e = 0; e < 8; ++e) b[e] = f2bf(Bs[bbase + e * BNP]);
            #pragma unroll
            for (int mt = 0; mt < 8; ++mt)
                acc[mt][nt] = __builtin_amdgcn_mfma_f32_16x16x32_bf16(a[mt], b, acc[mt][nt], 0, 0, 0);
        }
    }

    // epilogue: z'[m][j] = sum_h C[m][h] * S[m][h] ; reduce h across 16 lanes
    #pragma unroll
    for (int mt = 0; mt < 8; ++mt) {
        float ps0 = 0.f, ps1 = 0.f, ps2 = 0.f, ps3 = 0.f;
        const int mbase = wm * 128 + mt * 16 + lg * 4;
        #pragma unroll
        for (int nt = 0; nt < 3; ++nt) {
            int hh = wn * 48 + nt * 16 + l15;
            if (hh < H_SZ) {
                ps0 += acc[mt][nt][0] * S[(mbase + 0) * H_SZ + hh];
                ps1 += acc[mt][nt][1] * S[(mbase + 1) * H_SZ + hh];
                ps2 += acc[mt][nt][2] * S[(mbase + 2) * H_SZ + hh];
                ps3 += acc[mt][nt][3] * S[(mbase + 3) * H_SZ + hh];
            }
        }
        #pragma unroll
        for (int off = 8; off >= 1; off >>= 1) {
            ps0 += __shfl_xor(ps0, off, 16);
            ps1 += __shfl_xor(ps1, off, 16);
            ps2 += __shfl_xor(ps2, off, 16);
            ps3 += __shfl_xor(ps3, off, 16);
        }
        if (l15 == 0) {
            part[(mbase + 0) * 4 + wn] = ps0;
            part[(mbase + 1) * 4 + wn] = ps1;
            part[(mbase + 2) * 4 + wn] = ps2;
            part[(mbase + 3) * 4 + wn] = ps3;
        }
    }
    __syncthreads();
    if (tid < T_SZ) {
        float z = part[tid * 4] + part[tid * 4 + 1] + part[tid * 4 + 2] + part[tid * 4 + 3];
        zprime[tid * F_SZ + j] = z;
    }
}

// -------- K4: z -> selu -> @W2 + b2 -----------------------------------------
__global__ void __launch_bounds__(256) k4_out(const float* __restrict__ x,
                                              const float* __restrict__ h_all,
                                              const float* __restrict__ W1,
                                              const float* __restrict__ bupd,
                                              const float* __restrict__ b1,
                                              const float* __restrict__ W2,
                                              const float* __restrict__ b2,
                                              const float* __restrict__ zprime,
                                              float* __restrict__ out) {
    __shared__ float as[K_SZ];
    __shared__ float ys[256];
    int t = blockIdx.x;
    int tid = threadIdx.x;
    for (int i = tid; i < K_SZ; i += 256)
        as[i] = (i < I_SZ) ? x[t * I_SZ + i] : h_all[t * H_SZ + (i - I_SZ)];
    __syncthreads();
    if (tid < F_SZ) {
        float d1 = 0.f, d2 = 0.f;
        #pragma unroll 4
        for (int i = 0; i < K_SZ; ++i) {
            float av = as[i];
            d1 += av * W1[i * F_SZ + tid];
            d2 += av * bupd[i * F_SZ + tid];
        }
        float z = zprime[t * F_SZ + tid] + d1 + (float)t * d2 + b1[tid];
        const float scale = 1.0507009873554805f, alpha = 1.6732632423543772f;
        ys[tid] = z > 0.f ? scale * z : scale * alpha * (expf(z) - 1.f);
    }
    __syncthreads();
    #pragma unroll
    for (int rep = 0; rep < 2; ++rep) {
        int o = tid + rep * 256;
        float s = 0.f;
        #pragma unroll 2
        for (int jj = 0; jj < F_SZ; ++jj) s += ys[jj] * W2[jj * O_SZ + o];
        out[t * O_SZ + o] = s + b2[o];
    }
}

extern "C" void kernel_launch(void* const* d_in, const int* in_sizes, int n_in,
                              void* d_out, int out_size, void* d_ws, size_t ws_size,
                              hipStream_t stream) {
    const float* x    = (const float*)d_in[0];
    const float* h0   = (const float*)d_in[1];
    const float* Wrnn = (const float*)d_in[2];
    const float* brnn = (const float*)d_in[3];
    const float* Wupd = (const float*)d_in[4];
    const float* bupd = (const float*)d_in[5];
    const float* W1   = (const float*)d_in[6];
    const float* b1   = (const float*)d_in[7];
    const float* W2   = (const float*)d_in[8];
    const float* b2   = (const float*)d_in[9];
    float* out = (float*)d_out;

    float* ws = (float*)d_ws;
    float* P      = ws;                       // 48640
    float* h_all  = P + T_SZ * H_SZ;          // 48640
    float* S      = h_all + T_SZ * H_SZ;      // 48640
    float* zprime = S + T_SZ * H_SZ;          // 64000
    short* Abf    = (short*)(zprime + T_SZ * F_SZ);  // 262144 shorts (16B-aligned)

    k1_xproj <<<T_SZ, 256, 0, stream>>>(x, Wrnn, brnn, P);
    k2_scan  <<<1,    256, 0, stream>>>(Wrnn, h0, P, h_all, S);
    k2b_buildA<<<T_SZ, 256, 0, stream>>>(x, h_all, Abf);
    k3_mfma  <<<F_SZ, 512, 0, stream>>>(Wupd, Abf, S, zprime);
    k4_out   <<<T_SZ, 256, 0, stream>>>(x, h_all, W1, bupd, b1, W2, b2, zprime, out);
}